// Round 5
// baseline (1002.402 us; speedup 1.0000x reference)
//
#include <hip/hip_runtime.h>
#include <cstdint>
#include <cstddef>

// GAT 2-layer (N=8192, D=256), flash softmax with rank-1 scores, bf16 MFMA PV.
// Identities used:
//   leaky monotone  => m_i = leaky(s_i + max_{adj} d_j)
//   exp(leaky(x))   = max(e^x, e^{a x})
//   p_ij = adj ? max(Ep_i*F_j, Gp_i*H_j) : 0,  F=e^d, H=e^{a d},
//   Ep = rl*e^{s-m}, Gp = rl*e^{a s-m}, rl = 1/sum.
// pv is barrier-free: each wave owns (16 rows x 64 cols x 4096 K), generates its
// A-fragments in registers (no LDS), loads 4 pre-packed B-frags, 4 MFMAs/chunk.
// K-split x2 -> combine+relu kernel.
// ws (21 MB): Wh f32 @0 (8MB, dead after rowdots; pout_k1 aliases it) |
//             bits @8MB (8MB) | small arrays @16MB | Bpack @17MB (4MB)

#define ALPHA 0.2f
#define NN 8192
#define DD 256

typedef __attribute__((ext_vector_type(8))) short short8;
typedef __attribute__((ext_vector_type(4))) float f32x4;

__device__ __forceinline__ unsigned bf16rne(float x) {
    union { float f; unsigned u; } c; c.f = x;
    return (c.u + 0x7fffu + ((c.u >> 16) & 1u)) >> 16;
}

#if __has_builtin(__builtin_amdgcn_cvt_pk_bf16_f32)
__device__ __forceinline__ unsigned pk_bf16(float a, float b) {
    return __builtin_bit_cast(unsigned, __builtin_amdgcn_cvt_pk_bf16_f32(a, b));
}
#else
__device__ __forceinline__ unsigned pk_bf16(float a, float b) {
    return bf16rne(a) | (bf16rne(b) << 16);
}
#endif

// ---------------- packbits: adj int32 [8192][8192] -> bits uint64 [8192][128] ----------------
// 2048 blocks x 256 thr; wave = one row; 4 independent coalesced dword loads + 4 ballots/iter.
__global__ __launch_bounds__(256) void packbits(const int* __restrict__ adj,
                                                uint64_t* __restrict__ bits) {
    const int wid = blockIdx.x * 4 + (threadIdx.x >> 6);   // row 0..8191
    const int lane = threadIdx.x & 63;
    const int* rowp = adj + (size_t)wid * NN;
    uint64_t* dst = bits + (size_t)wid * 128;
    for (int it = 0; it < 32; it++) {
        const int* p = rowp + it * 256;
        int a0 = p[lane];
        int a1 = p[64 + lane];
        int a2 = p[128 + lane];
        int a3 = p[192 + lane];
        uint64_t m0 = __ballot(a0 != 0);
        uint64_t m1 = __ballot(a1 != 0);
        uint64_t m2 = __ballot(a2 != 0);
        uint64_t m3 = __ballot(a3 != 0);
        if (lane == 0) {
            dst[it * 4 + 0] = m0; dst[it * 4 + 1] = m1;
            dst[it * 4 + 2] = m2; dst[it * 4 + 3] = m3;
        }
    }
}

// ---------------- GEMM: Wh[8192 x 256] = A @ B[256 x 256], fp32 ----------------
// 512 blocks: 256 row-tiles (32) x 2 col-halves (128). Packs Wh into Bpack bf16
// MFMA-B panels: Bpack[((jt*16+ct)*64+lane)*8+q] = bf16(Wh[jt*32+(lane>>4)*8+q][ct*16+(lane&15)])
__global__ __launch_bounds__(256) void gemm_k256(const float* __restrict__ A,
                                                 const float* __restrict__ B,
                                                 float* __restrict__ C,
                                                 unsigned short* __restrict__ Bpack) {
    __shared__ __align__(16) float At[32][36];
    __shared__ __align__(16) float4 Bs[32][32];
    const int t = threadIdx.x;
    const int m0 = (int)(blockIdx.x >> 1) * 32;
    const int half = blockIdx.x & 1;
    const int r0 = (t >> 5) * 4;
    const int cl = t & 31;
    float acc[4][4];
#pragma unroll
    for (int i = 0; i < 4; i++)
#pragma unroll
        for (int j = 0; j < 4; j++) acc[i][j] = 0.f;

    for (int k0 = 0; k0 < DD; k0 += 32) {
        {
            int row = t >> 3, kq = t & 7;
            float4 v = *(const float4*)(A + (size_t)(m0 + row) * DD + k0 + kq * 4);
            At[kq * 4 + 0][row] = v.x; At[kq * 4 + 1][row] = v.y;
            At[kq * 4 + 2][row] = v.z; At[kq * 4 + 3][row] = v.w;
        }
#pragma unroll
        for (int l2 = 0; l2 < 4; l2++) {
            int fi = l2 * 256 + t;
            Bs[fi >> 5][fi & 31] =
                *(const float4*)(B + (size_t)(k0 + (fi >> 5)) * DD + half * 128 + (fi & 31) * 4);
        }
        __syncthreads();
#pragma unroll
        for (int k = 0; k < 32; k++) {
            float4 a0 = *(const float4*)&At[k][r0];
            float4 b0 = Bs[k][cl];
            float av[4] = {a0.x, a0.y, a0.z, a0.w};
            float bv[4] = {b0.x, b0.y, b0.z, b0.w};
#pragma unroll
            for (int i = 0; i < 4; i++)
#pragma unroll
                for (int j = 0; j < 4; j++) acc[i][j] += av[i] * bv[j];
        }
        __syncthreads();
    }
#pragma unroll
    for (int i = 0; i < 4; i++) {
        float4 v0 = {acc[i][0], acc[i][1], acc[i][2], acc[i][3]};
        *(float4*)(C + (size_t)(m0 + r0 + i) * DD + half * 128 + cl * 4) = v0;
    }
    const int jt = m0 >> 5;
    const int lq = ((r0 >> 3) & 3) * 16;
    const int i8 = r0 & 4;
#pragma unroll
    for (int cc = 0; cc < 4; cc++) {
        int c = half * 128 + cl * 4 + cc;
        int ct = c >> 4;
        int lane = lq + (c & 15);
        uint2 pk;
        pk.x = pk_bf16(acc[0][cc], acc[1][cc]);
        pk.y = pk_bf16(acc[2][cc], acc[3][cc]);
        *(uint2*)(Bpack + ((size_t)(jt * 16 + ct) * 64 + lane) * 8 + i8) = pk;
    }
}

// ------- s,d row dots; FH[2i]=exp(d), FH[2i+1]=exp(a*d) (1 wave/row) -------
__global__ __launch_bounds__(256) void rowdots(const float* __restrict__ Wh,
                                               const float* __restrict__ a_src,
                                               const float* __restrict__ a_dst,
                                               float* __restrict__ s,
                                               float* __restrict__ dd,
                                               float* __restrict__ FH) {
    int wave = threadIdx.x >> 6;
    int lane = threadIdx.x & 63;
    int row = blockIdx.x * 4 + wave;
    float4 w = *(const float4*)(Wh + (size_t)row * DD + lane * 4);
    float4 as = *(const float4*)(a_src + lane * 4);
    float4 ad = *(const float4*)(a_dst + lane * 4);
    float ss = w.x * as.x + w.y * as.y + w.z * as.z + w.w * as.w;
    float sd = w.x * ad.x + w.y * ad.y + w.z * ad.z + w.w * ad.w;
#pragma unroll
    for (int off = 32; off; off >>= 1) {
        ss += __shfl_down(ss, off);
        sd += __shfl_down(sd, off);
    }
    if (lane == 0) {
        s[row] = ss; dd[row] = sd;
        FH[2 * row] = __expf(sd);
        FH[2 * row + 1] = __expf(ALPHA * sd);
    }
}

// ------ rowstats: m = leaky(s + Dmax); sum = masked sum of max(em*F, ea*H); Ep, Gp ------
// 8192 blocks x 256 thr. Thread t owns j = [t*32, t*32+32). All loads independent.
__global__ __launch_bounds__(256) void rowstats(const uint32_t* __restrict__ bits32,
                                                const float* __restrict__ s,
                                                const float* __restrict__ dd,
                                                const float* __restrict__ FH,
                                                float* __restrict__ Ep,
                                                float* __restrict__ Gp) {
    __shared__ float wred[4];
    __shared__ float msh;
    const int i = blockIdx.x;
    const int t = threadIdx.x;
    const int wave = t >> 6, lane = t & 63;
    const float si = s[i];
    const uint32_t mk = bits32[(size_t)i * 256 + t];

    // phase A: Dmax
    float mx = -3.0e38f;
    const float* dp = dd + t * 32;
#pragma unroll
    for (int q = 0; q < 8; q++) {
        float4 v = *(const float4*)(dp + q * 4);
        uint32_t b = mk >> (q * 4);
        mx = fmaxf(mx, (b & 1u) ? v.x : -3.0e38f);
        mx = fmaxf(mx, (b & 2u) ? v.y : -3.0e38f);
        mx = fmaxf(mx, (b & 4u) ? v.z : -3.0e38f);
        mx = fmaxf(mx, (b & 8u) ? v.w : -3.0e38f);
    }
#pragma unroll
    for (int off = 32; off; off >>= 1) mx = fmaxf(mx, __shfl_down(mx, off));
    if (lane == 0) wred[wave] = mx;
    __syncthreads();
    if (t == 0) {
        float dmax = fmaxf(fmaxf(wred[0], wred[1]), fmaxf(wred[2], wred[3]));
        float e = si + dmax;
        msh = e >= 0.f ? e : ALPHA * e;
    }
    __syncthreads();
    const float m = msh;
    const float em = __expf(si - m);
    const float ea = __expf(ALPHA * si - m);

    // phase B: masked sum of max(em*F, ea*H)
    float sm = 0.f;
    const float* fp = FH + (size_t)t * 64;
#pragma unroll
    for (int q = 0; q < 16; q++) {
        float4 v = *(const float4*)(fp + q * 4);
        uint32_t b = mk >> (q * 2);
        float c0 = fmaxf(em * v.x, ea * v.y);
        float c1 = fmaxf(em * v.z, ea * v.w);
        sm += (b & 1u) ? c0 : 0.f;
        sm += (b & 2u) ? c1 : 0.f;
    }
#pragma unroll
    for (int off = 32; off; off >>= 1) sm += __shfl_down(sm, off);
    if (lane == 0) wred[wave] = sm;
    __syncthreads();
    if (t == 0) {
        float rl = 1.0f / (wred[0] + wred[1] + wred[2] + wred[3]);
        Ep[i] = rl * em;
        Gp[i] = rl * ea;
    }
}

// ---------------- PV via MFMA, barrier-free: partial = P @ Wh ----------------
// 1024 blocks x 256 thr. Wave task: iband (16 rows) x colq (64 cols) x khalf (4096 K).
// bx: khalf = bx&1, colq = (bx>>1)&3, ib4 = bx>>3; wave w -> iband = ib4*4+w.
// Blocks' 4 waves share the identical B stream (L1); (colq,khalf) = bx%8 pins the
// panel set to one XCD's L2. A-frags generated in registers; 4 MFMAs/chunk; no LDS.
__global__ __launch_bounds__(256) void pv_mfma(const unsigned short* __restrict__ Bpack,
                                               const uint32_t* __restrict__ bits32,
                                               const float* __restrict__ FH,
                                               const float* __restrict__ Ep,
                                               const float* __restrict__ Gp,
                                               float* __restrict__ out0,
                                               float* __restrict__ out1) {
    const int t = threadIdx.x;
    const int w = t >> 6, l = t & 63;
    const int bx = blockIdx.x;
    const int khalf = bx & 1;
    const int colq = (bx >> 1) & 3;
    const int ib4 = bx >> 3;
    const int i0 = (ib4 * 4 + w) * 16;
    const int c0 = colq * 4;                      // col-tile base (4 tiles of 16)
    const int cbase = khalf * 128;                // chunk base

    const int row = i0 + (l & 15);
    const int koff = (l >> 4) * 8;
    const float Epv = Ep[row];
    const float Gpv = Gp[row];
    const uint32_t* brow = bits32 + (size_t)row * 256;
    const unsigned short* bb = Bpack + (size_t)c0 * 512 + (size_t)l * 8;

    f32x4 acc[4];
#pragma unroll
    for (int q = 0; q < 4; q++) acc[q] = (f32x4){0.f, 0.f, 0.f, 0.f};

#pragma unroll 2
    for (int cc = cbase; cc < cbase + 128; cc++) {
        const int jj = cc * 32 + koff;
        const float* fhp = FH + 2 * (size_t)jj;
        float4 fh0 = *(const float4*)(fhp);
        float4 fh1 = *(const float4*)(fhp + 4);
        float4 fh2 = *(const float4*)(fhp + 8);
        float4 fh3 = *(const float4*)(fhp + 12);
        uint32_t wl = brow[cc] >> koff;
        const unsigned short* bp = bb + (size_t)cc * 8192;
        short8 b0 = *(const short8*)(bp);
        short8 b1 = *(const short8*)(bp + 512);
        short8 b2 = *(const short8*)(bp + 1024);
        short8 b3 = *(const short8*)(bp + 1536);

        float p0 = (wl & 1u)   ? fmaxf(Epv * fh0.x, Gpv * fh0.y) : 0.f;
        float p1 = (wl & 2u)   ? fmaxf(Epv * fh0.z, Gpv * fh0.w) : 0.f;
        float p2 = (wl & 4u)   ? fmaxf(Epv * fh1.x, Gpv * fh1.y) : 0.f;
        float p3 = (wl & 8u)   ? fmaxf(Epv * fh1.z, Gpv * fh1.w) : 0.f;
        float p4 = (wl & 16u)  ? fmaxf(Epv * fh2.x, Gpv * fh2.y) : 0.f;
        float p5 = (wl & 32u)  ? fmaxf(Epv * fh2.z, Gpv * fh2.w) : 0.f;
        float p6 = (wl & 64u)  ? fmaxf(Epv * fh3.x, Gpv * fh3.y) : 0.f;
        float p7 = (wl & 128u) ? fmaxf(Epv * fh3.z, Gpv * fh3.w) : 0.f;
        uint32_t k0 = pk_bf16(p0, p1);
        uint32_t k1 = pk_bf16(p2, p3);
        uint32_t k2 = pk_bf16(p4, p5);
        uint32_t k3 = pk_bf16(p6, p7);
        uint4 au = {k0, k1, k2, k3};
        short8 af = __builtin_bit_cast(short8, au);

        acc[0] = __builtin_amdgcn_mfma_f32_16x16x32_bf16(af, b0, acc[0], 0, 0, 0);
        acc[1] = __builtin_amdgcn_mfma_f32_16x16x32_bf16(af, b1, acc[1], 0, 0, 0);
        acc[2] = __builtin_amdgcn_mfma_f32_16x16x32_bf16(af, b2, acc[2], 0, 0, 0);
        acc[3] = __builtin_amdgcn_mfma_f32_16x16x32_bf16(af, b3, acc[3], 0, 0, 0);
    }

    float* outp = khalf ? out1 : out0;
    // C layout: col = l&15, row = (l>>4)*4 + r
#pragma unroll
    for (int q = 0; q < 4; q++) {
        const int ocol = (c0 + q) * 16 + (l & 15);
        const int orow = i0 + (l >> 4) * 4;
#pragma unroll
        for (int r = 0; r < 4; r++) {
            outp[(size_t)(orow + r) * DD + ocol] = acc[q][r];
        }
    }
}

// -------- out = relu(out + pw) --------
__global__ __launch_bounds__(256) void combine_relu(float* __restrict__ out,
                                                    const float* __restrict__ pw) {
    int idx = blockIdx.x * 256 + threadIdx.x;
    float4 a = ((const float4*)out)[idx];
    float4 b = ((const float4*)pw)[idx];
    float4 o;
    o.x = fmaxf(a.x + b.x, 0.f);
    o.y = fmaxf(a.y + b.y, 0.f);
    o.z = fmaxf(a.z + b.z, 0.f);
    o.w = fmaxf(a.w + b.w, 0.f);
    ((float4*)out)[idx] = o;
}

extern "C" void kernel_launch(void* const* d_in, const int* in_sizes, int n_in,
                              void* d_out, int out_size, void* d_ws, size_t ws_size,
                              hipStream_t stream) {
    const float* x   = (const float*)d_in[0];
    const int* adj   = (const int*)d_in[1];
    const float* W1  = (const float*)d_in[2];
    const float* a1s = (const float*)d_in[3];
    const float* a1d = (const float*)d_in[4];
    const float* W2  = (const float*)d_in[5];
    const float* a2s = (const float*)d_in[6];
    const float* a2d = (const float*)d_in[7];
    float* out = (float*)d_out;

    char* ws = (char*)d_ws;
    const size_t MB = 1024ull * 1024ull;
    float*          Wh    = (float*)(ws);                    // 8 MB (dead after rowdots)
    float*          pw    = (float*)(ws);                    // pout khalf=1 aliases Wh
    uint64_t*       bits  = (uint64_t*)(ws + 8 * MB);        // 8 MB
    uint32_t*       bits32= (uint32_t*)bits;
    float*          sArr  = (float*)(ws + 16 * MB);
    float*          ddA   = sArr + NN;
    float*          EpA   = sArr + 2 * NN;
    float*          GpA   = sArr + 3 * NN;
    float*          FHA   = sArr + 4 * NN;                   // 2*NN floats
    unsigned short* Bpack = (unsigned short*)(ws + 17 * MB); // 4 MB

    packbits<<<dim3(2048), dim3(256), 0, stream>>>(adj, bits);

    // ---------------- Layer 1 ----------------
    gemm_k256<<<dim3(512), dim3(256), 0, stream>>>(x, W1, Wh, Bpack);
    rowdots<<<dim3(2048), dim3(256), 0, stream>>>(Wh, a1s, a1d, sArr, ddA, FHA);
    rowstats<<<dim3(NN), dim3(256), 0, stream>>>(bits32, sArr, ddA, FHA, EpA, GpA);
    pv_mfma<<<dim3(1024), dim3(256), 0, stream>>>(Bpack, bits32, FHA, EpA, GpA, out, pw);
    combine_relu<<<dim3(2048), dim3(256), 0, stream>>>(out, pw);

    // ---------------- Layer 2 ----------------
    gemm_k256<<<dim3(512), dim3(256), 0, stream>>>(out, W2, Wh, Bpack);
    rowdots<<<dim3(2048), dim3(256), 0, stream>>>(Wh, a2s, a2d, sArr, ddA, FHA);
    rowstats<<<dim3(NN), dim3(256), 0, stream>>>(bits32, sArr, ddA, FHA, EpA, GpA);
    pv_mfma<<<dim3(1024), dim3(256), 0, stream>>>(Bpack, bits32, FHA, EpA, GpA, out, pw);
    combine_relu<<<dim3(2048), dim3(256), 0, stream>>>(out, pw);
}

// Round 6
// 838.595 us; speedup vs baseline: 1.1953x; 1.1953x over previous
//
#include <hip/hip_runtime.h>
#include <cstdint>
#include <cstddef>

// GAT 2-layer (N=8192, D=256), flash softmax with rank-1 scores, bf16 MFMA PV.
// Identities:
//   m_i = leaky(s_i + max_{adj} d_j)        (leaky monotone)
//   exp(leaky(x)) = max(e^x, e^{a x})
//   p_ij = adj ? max(Ep_i*F_j, Gp_i*H_j) : 0,  F=e^d, H=e^{a d} (FH interleaved),
//   Ep = rl*e^{s-m}, Gp = rl*e^{a s-m}.
// pv v3: block = 32 rows x 128 cols, 4 waves; each wave covers all 32 rows x 64 cols
// (2 A-frags x 2 B-frags = 4 MFMA/chunk) so B is partitioned across waves:
// 512 B-bytes per MFMA (R5 was 1KB). A generated into LDS frag-order (dbuf, one
// barrier/chunk); B prefetched to VGPRs across the barrier. Grid 1024 = 4 blocks/CU.
// ws (21 MB): Wh f32 @0 (8MB, dead after rowdots; pv khalf=1 partial aliases it) |
//             bits @8MB (8MB) | small arrays @16MB | Bpack @17MB (4MB)

#define ALPHA 0.2f
#define NN 8192
#define DD 256

typedef __attribute__((ext_vector_type(8))) short short8;
typedef __attribute__((ext_vector_type(4))) float f32x4;

__device__ __forceinline__ unsigned bf16rne(float x) {
    union { float f; unsigned u; } c; c.f = x;
    return (c.u + 0x7fffu + ((c.u >> 16) & 1u)) >> 16;
}

#if __has_builtin(__builtin_amdgcn_cvt_pk_bf16_f32)
__device__ __forceinline__ unsigned pk_bf16(float a, float b) {
    return __builtin_bit_cast(unsigned, __builtin_amdgcn_cvt_pk_bf16_f32(a, b));
}
#else
__device__ __forceinline__ unsigned pk_bf16(float a, float b) {
    return bf16rne(a) | (bf16rne(b) << 16);
}
#endif

// ---------------- packbits: adj int32 [8192][8192] -> bits uint64 [8192][128] ----------------
__global__ __launch_bounds__(256) void packbits(const int* __restrict__ adj,
                                                uint64_t* __restrict__ bits) {
    const int wid = blockIdx.x * 4 + (threadIdx.x >> 6);
    const int lane = threadIdx.x & 63;
    const int* rowp = adj + (size_t)wid * NN;
    uint64_t* dst = bits + (size_t)wid * 128;
    for (int it = 0; it < 32; it++) {
        const int* p = rowp + it * 256;
        int a0 = p[lane];
        int a1 = p[64 + lane];
        int a2 = p[128 + lane];
        int a3 = p[192 + lane];
        uint64_t m0 = __ballot(a0 != 0);
        uint64_t m1 = __ballot(a1 != 0);
        uint64_t m2 = __ballot(a2 != 0);
        uint64_t m3 = __ballot(a3 != 0);
        if (lane == 0) {
            dst[it * 4 + 0] = m0; dst[it * 4 + 1] = m1;
            dst[it * 4 + 2] = m2; dst[it * 4 + 3] = m3;
        }
    }
}

// ---------------- GEMM: Wh[8192 x 256] = A @ B[256 x 256], fp32 ----------------
// 512 blocks: 256 row-tiles (32) x 2 col-halves (128). Packs Wh into Bpack bf16
// MFMA-B panels: Bpack[((jt*16+ct)*64+lane)*8+q] = bf16(Wh[jt*32+(lane>>4)*8+q][ct*16+(lane&15)])
__global__ __launch_bounds__(256) void gemm_k256(const float* __restrict__ A,
                                                 const float* __restrict__ B,
                                                 float* __restrict__ C,
                                                 unsigned short* __restrict__ Bpack) {
    __shared__ __align__(16) float At[32][36];
    __shared__ __align__(16) float4 Bs[32][32];
    const int t = threadIdx.x;
    const int m0 = (int)(blockIdx.x >> 1) * 32;
    const int half = blockIdx.x & 1;
    const int r0 = (t >> 5) * 4;
    const int cl = t & 31;
    float acc[4][4];
#pragma unroll
    for (int i = 0; i < 4; i++)
#pragma unroll
        for (int j = 0; j < 4; j++) acc[i][j] = 0.f;

    for (int k0 = 0; k0 < DD; k0 += 32) {
        {
            int row = t >> 3, kq = t & 7;
            float4 v = *(const float4*)(A + (size_t)(m0 + row) * DD + k0 + kq * 4);
            At[kq * 4 + 0][row] = v.x; At[kq * 4 + 1][row] = v.y;
            At[kq * 4 + 2][row] = v.z; At[kq * 4 + 3][row] = v.w;
        }
#pragma unroll
        for (int l2 = 0; l2 < 4; l2++) {
            int fi = l2 * 256 + t;
            Bs[fi >> 5][fi & 31] =
                *(const float4*)(B + (size_t)(k0 + (fi >> 5)) * DD + half * 128 + (fi & 31) * 4);
        }
        __syncthreads();
#pragma unroll
        for (int k = 0; k < 32; k++) {
            float4 a0 = *(const float4*)&At[k][r0];
            float4 b0 = Bs[k][cl];
            float av[4] = {a0.x, a0.y, a0.z, a0.w};
            float bv[4] = {b0.x, b0.y, b0.z, b0.w};
#pragma unroll
            for (int i = 0; i < 4; i++)
#pragma unroll
                for (int j = 0; j < 4; j++) acc[i][j] += av[i] * bv[j];
        }
        __syncthreads();
    }
#pragma unroll
    for (int i = 0; i < 4; i++) {
        float4 v0 = {acc[i][0], acc[i][1], acc[i][2], acc[i][3]};
        *(float4*)(C + (size_t)(m0 + r0 + i) * DD + half * 128 + cl * 4) = v0;
    }
    const int jt = m0 >> 5;
    const int lq = ((r0 >> 3) & 3) * 16;
    const int i8 = r0 & 4;
#pragma unroll
    for (int cc = 0; cc < 4; cc++) {
        int c = half * 128 + cl * 4 + cc;
        int ct = c >> 4;
        int lane = lq + (c & 15);
        uint2 pk;
        pk.x = pk_bf16(acc[0][cc], acc[1][cc]);
        pk.y = pk_bf16(acc[2][cc], acc[3][cc]);
        *(uint2*)(Bpack + ((size_t)(jt * 16 + ct) * 64 + lane) * 8 + i8) = pk;
    }
}

// ------- s,d row dots; FH[2i]=exp(d), FH[2i+1]=exp(a*d) (1 wave/row) -------
__global__ __launch_bounds__(256) void rowdots(const float* __restrict__ Wh,
                                               const float* __restrict__ a_src,
                                               const float* __restrict__ a_dst,
                                               float* __restrict__ s,
                                               float* __restrict__ dd,
                                               float* __restrict__ FH) {
    int wave = threadIdx.x >> 6;
    int lane = threadIdx.x & 63;
    int row = blockIdx.x * 4 + wave;
    float4 w = *(const float4*)(Wh + (size_t)row * DD + lane * 4);
    float4 as = *(const float4*)(a_src + lane * 4);
    float4 ad = *(const float4*)(a_dst + lane * 4);
    float ss = w.x * as.x + w.y * as.y + w.z * as.z + w.w * as.w;
    float sd = w.x * ad.x + w.y * ad.y + w.z * ad.z + w.w * ad.w;
#pragma unroll
    for (int off = 32; off; off >>= 1) {
        ss += __shfl_down(ss, off);
        sd += __shfl_down(sd, off);
    }
    if (lane == 0) {
        s[row] = ss; dd[row] = sd;
        FH[2 * row] = __expf(sd);
        FH[2 * row + 1] = __expf(ALPHA * sd);
    }
}

// ------ rowstats: m = leaky(s + Dmax); sum = masked sum of max(em*F, ea*H); Ep, Gp ------
__global__ __launch_bounds__(256) void rowstats(const uint32_t* __restrict__ bits32,
                                                const float* __restrict__ s,
                                                const float* __restrict__ dd,
                                                const float* __restrict__ FH,
                                                float* __restrict__ Ep,
                                                float* __restrict__ Gp) {
    __shared__ float wred[4];
    __shared__ float msh;
    const int i = blockIdx.x;
    const int t = threadIdx.x;
    const int wave = t >> 6, lane = t & 63;
    const float si = s[i];
    const uint32_t mk = bits32[(size_t)i * 256 + t];

    float mx = -3.0e38f;
    const float* dp = dd + t * 32;
#pragma unroll
    for (int q = 0; q < 8; q++) {
        float4 v = *(const float4*)(dp + q * 4);
        uint32_t b = mk >> (q * 4);
        mx = fmaxf(mx, (b & 1u) ? v.x : -3.0e38f);
        mx = fmaxf(mx, (b & 2u) ? v.y : -3.0e38f);
        mx = fmaxf(mx, (b & 4u) ? v.z : -3.0e38f);
        mx = fmaxf(mx, (b & 8u) ? v.w : -3.0e38f);
    }
#pragma unroll
    for (int off = 32; off; off >>= 1) mx = fmaxf(mx, __shfl_down(mx, off));
    if (lane == 0) wred[wave] = mx;
    __syncthreads();
    if (t == 0) {
        float dmax = fmaxf(fmaxf(wred[0], wred[1]), fmaxf(wred[2], wred[3]));
        float e = si + dmax;
        msh = e >= 0.f ? e : ALPHA * e;
    }
    __syncthreads();
    const float m = msh;
    const float em = __expf(si - m);
    const float ea = __expf(ALPHA * si - m);

    float sm = 0.f;
    const float* fp = FH + (size_t)t * 64;
#pragma unroll
    for (int q = 0; q < 16; q++) {
        float4 v = *(const float4*)(fp + q * 4);
        uint32_t b = mk >> (q * 2);
        float c0 = fmaxf(em * v.x, ea * v.y);
        float c1 = fmaxf(em * v.z, ea * v.w);
        sm += (b & 1u) ? c0 : 0.f;
        sm += (b & 2u) ? c1 : 0.f;
    }
#pragma unroll
    for (int off = 32; off; off >>= 1) sm += __shfl_down(sm, off);
    if (lane == 0) wred[wave] = sm;
    __syncthreads();
    if (t == 0) {
        float rl = 1.0f / (wred[0] + wred[1] + wred[2] + wred[3]);
        Ep[i] = rl * em;
        Gp[i] = rl * ea;
    }
}

// ---------------- PV via MFMA: partial = P @ Wh ----------------
// 1024 blocks x 256 thr: bx -> khalf = bx&1, chalf = (bx>>1)&1, it = bx>>2.
// Block tile: 32 rows x 128 cols, K-half 4096. Wave w: all 32 rows x cols
// [chalf*128 + w*32, +32) = col-tiles ct0=chalf*8+2w, ct0+1. 4 MFMA/wave/chunk.
// A (P) generated cooperatively into LDS frag order, double-buffered, one
// barrier per chunk; B-frags prefetched to VGPRs across the barrier.
__global__ __launch_bounds__(256, 4) void pv_mfma(const unsigned short* __restrict__ Bpack,
                                                  const uint32_t* __restrict__ bits32,
                                                  const float* __restrict__ FH,
                                                  const float* __restrict__ Ep,
                                                  const float* __restrict__ Gp,
                                                  float* __restrict__ out0,
                                                  float* __restrict__ out1) {
    __shared__ __align__(16) unsigned short fragA[2][2 * 64 * 8];  // [buf][(rb*64+l)*8], 4KB
    const int t = threadIdx.x;
    const int w = t >> 6, l = t & 63;
    const int bx = blockIdx.x;
    const int khalf = bx & 1;
    const int chalf = (bx >> 1) & 1;
    const int i0 = (bx >> 2) * 32;
    const int kbase = khalf * 128;                 // chunk base (128 chunks per half)
    const int ct0 = chalf * 8 + 2 * w;             // wave's first col-tile

    // ---- P-gen mapping: thread t -> (row rr = t>>3 of 32, k-quad kq = t&7), 4 P ----
    const int rr = t >> 3;
    const int kq = t & 7;
    const int grow = i0 + rr;
    const float Epv = Ep[grow];
    const float Gpv = Gp[grow];
    const uint32_t* brow = bits32 + (size_t)grow * 256;
    // LDS slot: rb = rr>>4, lane = (kq>>1)*16 + (rr&15), short-offset (kq&1)*4
    const int wslot = (((rr >> 4) * 64 + (kq >> 1) * 16 + (rr & 15)) * 8 + (kq & 1) * 4) >> 2;

    auto gen = [&](int cc, int nbuf) {
        const int jj = cc * 32 + kq * 4;
        const float* fhp = FH + 2 * (size_t)jj;
        float4 fh0 = *(const float4*)(fhp);
        float4 fh1 = *(const float4*)(fhp + 4);
        uint32_t wl = brow[cc] >> (kq * 4);
        float p0 = (wl & 1u) ? fmaxf(Epv * fh0.x, Gpv * fh0.y) : 0.f;
        float p1 = (wl & 2u) ? fmaxf(Epv * fh0.z, Gpv * fh0.w) : 0.f;
        float p2 = (wl & 4u) ? fmaxf(Epv * fh1.x, Gpv * fh1.y) : 0.f;
        float p3 = (wl & 8u) ? fmaxf(Epv * fh1.z, Gpv * fh1.w) : 0.f;
        uint2 pk;
        pk.x = pk_bf16(p0, p1);
        pk.y = pk_bf16(p2, p3);
        ((uint2*)&fragA[nbuf][0])[wslot] = pk;
    };

    const unsigned short* bb = Bpack + ((size_t)ct0 * 64 + l) * 8;

    f32x4 acc[2][2];
#pragma unroll
    for (int i = 0; i < 2; i++)
#pragma unroll
        for (int q = 0; q < 2; q++) acc[i][q] = (f32x4){0.f, 0.f, 0.f, 0.f};

    // prologue
    gen(kbase, 0);
    short8 Bc0, Bc1;
    {
        const unsigned short* bp = bb + (size_t)kbase * 8192;
        Bc0 = *(const short8*)bp;
        Bc1 = *(const short8*)(bp + 512);
    }
    __syncthreads();

    for (int jl = 0; jl < 128; jl++) {
        const int buf = jl & 1;
        const int cn = kbase + ((jl + 1) & 127);
        // prefetch next B -> VGPRs (in flight across this iteration's barrier)
        const unsigned short* bp = bb + (size_t)cn * 8192;
        short8 Bn0 = *(const short8*)bp;
        short8 Bn1 = *(const short8*)(bp + 512);
        // generate next P tile into the other LDS buffer
        gen(cn, buf ^ 1);
        // consume current chunk: 2 A-frags x 2 B-frags
        short8 a0 = *(const short8*)&fragA[buf][l * 8];
        short8 a1 = *(const short8*)&fragA[buf][(64 + l) * 8];
        acc[0][0] = __builtin_amdgcn_mfma_f32_16x16x32_bf16(a0, Bc0, acc[0][0], 0, 0, 0);
        acc[0][1] = __builtin_amdgcn_mfma_f32_16x16x32_bf16(a0, Bc1, acc[0][1], 0, 0, 0);
        acc[1][0] = __builtin_amdgcn_mfma_f32_16x16x32_bf16(a1, Bc0, acc[1][0], 0, 0, 0);
        acc[1][1] = __builtin_amdgcn_mfma_f32_16x16x32_bf16(a1, Bc1, acc[1][1], 0, 0, 0);
        __syncthreads();
        Bc0 = Bn0; Bc1 = Bn1;
    }

    float* outp = khalf ? out1 : out0;
    // C layout: col = l&15, row = (l>>4)*4 + r
#pragma unroll
    for (int rb = 0; rb < 2; rb++) {
        const int orow = i0 + rb * 16 + (l >> 4) * 4;
#pragma unroll
        for (int q = 0; q < 2; q++) {
            const int ocol = (ct0 + q) * 16 + (l & 15);
#pragma unroll
            for (int r = 0; r < 4; r++) {
                outp[(size_t)(orow + r) * DD + ocol] = acc[rb][q][r];
            }
        }
    }
}

// -------- out = relu(out + pw) --------
__global__ __launch_bounds__(256) void combine_relu(float* __restrict__ out,
                                                    const float* __restrict__ pw) {
    int idx = blockIdx.x * 256 + threadIdx.x;
    float4 a = ((const float4*)out)[idx];
    float4 b = ((const float4*)pw)[idx];
    float4 o;
    o.x = fmaxf(a.x + b.x, 0.f);
    o.y = fmaxf(a.y + b.y, 0.f);
    o.z = fmaxf(a.z + b.z, 0.f);
    o.w = fmaxf(a.w + b.w, 0.f);
    ((float4*)out)[idx] = o;
}

extern "C" void kernel_launch(void* const* d_in, const int* in_sizes, int n_in,
                              void* d_out, int out_size, void* d_ws, size_t ws_size,
                              hipStream_t stream) {
    const float* x   = (const float*)d_in[0];
    const int* adj   = (const int*)d_in[1];
    const float* W1  = (const float*)d_in[2];
    const float* a1s = (const float*)d_in[3];
    const float* a1d = (const float*)d_in[4];
    const float* W2  = (const float*)d_in[5];
    const float* a2s = (const float*)d_in[6];
    const float* a2d = (const float*)d_in[7];
    float* out = (float*)d_out;

    char* ws = (char*)d_ws;
    const size_t MB = 1024ull * 1024ull;
    float*          Wh    = (float*)(ws);                    // 8 MB (dead after rowdots)
    float*          pw    = (float*)(ws);                    // pv khalf=1 partial aliases Wh
    uint64_t*       bits  = (uint64_t*)(ws + 8 * MB);        // 8 MB
    uint32_t*       bits32= (uint32_t*)bits;
    float*          sArr  = (float*)(ws + 16 * MB);
    float*          ddA   = sArr + NN;
    float*          EpA   = sArr + 2 * NN;
    float*          GpA   = sArr + 3 * NN;
    float*          FHA   = sArr + 4 * NN;                   // 2*NN floats
    unsigned short* Bpack = (unsigned short*)(ws + 17 * MB); // 4 MB

    packbits<<<dim3(2048), dim3(256), 0, stream>>>(adj, bits);

    // ---------------- Layer 1 ----------------
    gemm_k256<<<dim3(512), dim3(256), 0, stream>>>(x, W1, Wh, Bpack);
    rowdots<<<dim3(2048), dim3(256), 0, stream>>>(Wh, a1s, a1d, sArr, ddA, FHA);
    rowstats<<<dim3(NN), dim3(256), 0, stream>>>(bits32, sArr, ddA, FHA, EpA, GpA);
    pv_mfma<<<dim3(1024), dim3(256), 0, stream>>>(Bpack, bits32, FHA, EpA, GpA, out, pw);
    combine_relu<<<dim3(2048), dim3(256), 0, stream>>>(out, pw);

    // ---------------- Layer 2 ----------------
    gemm_k256<<<dim3(512), dim3(256), 0, stream>>>(out, W2, Wh, Bpack);
    rowdots<<<dim3(2048), dim3(256), 0, stream>>>(Wh, a2s, a2d, sArr, ddA, FHA);
    rowstats<<<dim3(NN), dim3(256), 0, stream>>>(bits32, sArr, ddA, FHA, EpA, GpA);
    pv_mfma<<<dim3(1024), dim3(256), 0, stream>>>(Bpack, bits32, FHA, EpA, GpA, out, pw);
    combine_relu<<<dim3(2048), dim3(256), 0, stream>>>(out, pw);
}

// Round 7
// 740.459 us; speedup vs baseline: 1.3538x; 1.1325x over previous
//
#include <hip/hip_runtime.h>
#include <cstdint>
#include <cstddef>

// GAT 2-layer (N=8192, D=256), flash softmax with rank-1 scores, bf16 MFMA PV.
// Identities:
//   m_i = leaky(s_i + max_{adj} d_j)        (leaky monotone)
//   exp(leaky(x)) = max(e^x, e^{a x})
//   p_ij = adj ? max(Ep_i*F_j, Gp_i*H_j) : 0,  F=e^d, H=e^{a d} (FH interleaved),
//   Ep = rl*e^{s-m}, Gp = rl*e^{a s-m}.
// pv v4: block = 128 rows x 128 cols x K/4 (512 blocks, 256 thr, 4 waves).
// Wave = 64x64 = 4 A-frags x 4 B-frags = 16 MFMA/chunk (0.5 KB fragment feed per
// MFMA). A generated into LDS frag-order (dbuf, 1 barrier/chunk); B register-
// prefetched one chunk ahead. bitsT gives lane-contiguous mask reads.
// ws (64 MB): Wh @0 (8) | bits @8 (8) | bitsT @16 (8) | small @24 | Bpack @25 (4)
//             | pout @32 (4 x 8 MB k-split partials)

#define ALPHA 0.2f
#define NN 8192
#define DD 256

typedef __attribute__((ext_vector_type(8))) short short8;
typedef __attribute__((ext_vector_type(4))) float f32x4;

__device__ __forceinline__ unsigned bf16rne(float x) {
    union { float f; unsigned u; } c; c.f = x;
    return (c.u + 0x7fffu + ((c.u >> 16) & 1u)) >> 16;
}

#if __has_builtin(__builtin_amdgcn_cvt_pk_bf16_f32)
__device__ __forceinline__ unsigned pk_bf16(float a, float b) {
    return __builtin_bit_cast(unsigned, __builtin_amdgcn_cvt_pk_bf16_f32(a, b));
}
#else
__device__ __forceinline__ unsigned pk_bf16(float a, float b) {
    return bf16rne(a) | (bf16rne(b) << 16);
}
#endif

// ---------------- packbits: adj int32 [8192][8192] -> bits uint32 [8192][256] ----------------
__global__ __launch_bounds__(256) void packbits(const int* __restrict__ adj,
                                                uint64_t* __restrict__ bits) {
    const int wid = blockIdx.x * 4 + (threadIdx.x >> 6);
    const int lane = threadIdx.x & 63;
    const int* rowp = adj + (size_t)wid * NN;
    uint64_t* dst = bits + (size_t)wid * 128;
    for (int it = 0; it < 32; it++) {
        const int* p = rowp + it * 256;
        int a0 = p[lane];
        int a1 = p[64 + lane];
        int a2 = p[128 + lane];
        int a3 = p[192 + lane];
        uint64_t m0 = __ballot(a0 != 0);
        uint64_t m1 = __ballot(a1 != 0);
        uint64_t m2 = __ballot(a2 != 0);
        uint64_t m3 = __ballot(a3 != 0);
        if (lane == 0) {
            dst[it * 4 + 0] = m0; dst[it * 4 + 1] = m1;
            dst[it * 4 + 2] = m2; dst[it * 4 + 3] = m3;
        }
    }
}

// ---------------- bits [i][w] -> bitsT [w][i] (64x64 dword tiles) ----------------
__global__ __launch_bounds__(256) void transp_bits(const uint32_t* __restrict__ bits32,
                                                   uint32_t* __restrict__ bitsT) {
    __shared__ uint32_t tile[64][65];
    const int t = threadIdx.x;
    const int i0 = (int)(blockIdx.x >> 2) * 64;
    const int w0 = (int)(blockIdx.x & 3) * 64;
#pragma unroll
    for (int p = 0; p < 4; p++) {
        int r = (t >> 4) + 16 * p;
        int c4 = (t & 15) * 4;
        uint4 v = *(const uint4*)(bits32 + (size_t)(i0 + r) * 256 + w0 + c4);
        tile[r][c4 + 0] = v.x; tile[r][c4 + 1] = v.y;
        tile[r][c4 + 2] = v.z; tile[r][c4 + 3] = v.w;
    }
    __syncthreads();
#pragma unroll
    for (int p = 0; p < 4; p++) {
        int wr = (t >> 4) + 16 * p;
        int i4 = (t & 15) * 4;
        uint4 o = {tile[i4][wr], tile[i4 + 1][wr], tile[i4 + 2][wr], tile[i4 + 3][wr]};
        *(uint4*)(bitsT + (size_t)(w0 + wr) * NN + i0 + i4) = o;
    }
}

// ---------------- GEMM: Wh[8192 x 256] = A @ B[256 x 256], fp32; packs Bpack ----------------
__global__ __launch_bounds__(256) void gemm_k256(const float* __restrict__ A,
                                                 const float* __restrict__ B,
                                                 float* __restrict__ C,
                                                 unsigned short* __restrict__ Bpack) {
    __shared__ __align__(16) float At[32][36];
    __shared__ __align__(16) float4 Bs[32][32];
    const int t = threadIdx.x;
    const int m0 = (int)(blockIdx.x >> 1) * 32;
    const int half = blockIdx.x & 1;
    const int r0 = (t >> 5) * 4;
    const int cl = t & 31;
    float acc[4][4];
#pragma unroll
    for (int i = 0; i < 4; i++)
#pragma unroll
        for (int j = 0; j < 4; j++) acc[i][j] = 0.f;

    for (int k0 = 0; k0 < DD; k0 += 32) {
        {
            int row = t >> 3, kq = t & 7;
            float4 v = *(const float4*)(A + (size_t)(m0 + row) * DD + k0 + kq * 4);
            At[kq * 4 + 0][row] = v.x; At[kq * 4 + 1][row] = v.y;
            At[kq * 4 + 2][row] = v.z; At[kq * 4 + 3][row] = v.w;
        }
#pragma unroll
        for (int l2 = 0; l2 < 4; l2++) {
            int fi = l2 * 256 + t;
            Bs[fi >> 5][fi & 31] =
                *(const float4*)(B + (size_t)(k0 + (fi >> 5)) * DD + half * 128 + (fi & 31) * 4);
        }
        __syncthreads();
#pragma unroll
        for (int k = 0; k < 32; k++) {
            float4 a0 = *(const float4*)&At[k][r0];
            float4 b0 = Bs[k][cl];
            float av[4] = {a0.x, a0.y, a0.z, a0.w};
            float bv[4] = {b0.x, b0.y, b0.z, b0.w};
#pragma unroll
            for (int i = 0; i < 4; i++)
#pragma unroll
                for (int j = 0; j < 4; j++) acc[i][j] += av[i] * bv[j];
        }
        __syncthreads();
    }
#pragma unroll
    for (int i = 0; i < 4; i++) {
        float4 v0 = {acc[i][0], acc[i][1], acc[i][2], acc[i][3]};
        *(float4*)(C + (size_t)(m0 + r0 + i) * DD + half * 128 + cl * 4) = v0;
    }
    const int jt = m0 >> 5;
    const int lq = ((r0 >> 3) & 3) * 16;
    const int i8 = r0 & 4;
#pragma unroll
    for (int cc = 0; cc < 4; cc++) {
        int c = half * 128 + cl * 4 + cc;
        int ct = c >> 4;
        int lane = lq + (c & 15);
        uint2 pk;
        pk.x = pk_bf16(acc[0][cc], acc[1][cc]);
        pk.y = pk_bf16(acc[2][cc], acc[3][cc]);
        *(uint2*)(Bpack + ((size_t)(jt * 16 + ct) * 64 + lane) * 8 + i8) = pk;
    }
}

// ------- s,d row dots; FH[2i]=exp(d), FH[2i+1]=exp(a*d) (1 wave/row) -------
__global__ __launch_bounds__(256) void rowdots(const float* __restrict__ Wh,
                                               const float* __restrict__ a_src,
                                               const float* __restrict__ a_dst,
                                               float* __restrict__ s,
                                               float* __restrict__ dd,
                                               float* __restrict__ FH) {
    int wave = threadIdx.x >> 6;
    int lane = threadIdx.x & 63;
    int row = blockIdx.x * 4 + wave;
    float4 w = *(const float4*)(Wh + (size_t)row * DD + lane * 4);
    float4 as = *(const float4*)(a_src + lane * 4);
    float4 ad = *(const float4*)(a_dst + lane * 4);
    float ss = w.x * as.x + w.y * as.y + w.z * as.z + w.w * as.w;
    float sd = w.x * ad.x + w.y * ad.y + w.z * ad.z + w.w * ad.w;
#pragma unroll
    for (int off = 32; off; off >>= 1) {
        ss += __shfl_down(ss, off);
        sd += __shfl_down(sd, off);
    }
    if (lane == 0) {
        s[row] = ss; dd[row] = sd;
        FH[2 * row] = __expf(sd);
        FH[2 * row + 1] = __expf(ALPHA * sd);
    }
}

// ------ rowstats v3: 8 rows/block, lane-contiguous loads, masks via LDS ------
__global__ __launch_bounds__(256) void rowstats(const uint32_t* __restrict__ bits32,
                                                const float* __restrict__ s,
                                                const float* __restrict__ dd,
                                                const float* __restrict__ FH,
                                                float* __restrict__ Ep,
                                                float* __restrict__ Gp) {
    __shared__ uint32_t smk[2048];          // 8 rows x 256 words
    __shared__ float red[4][8];
    __shared__ float sM[8], sEm[8], sEa[8];
    const int i0 = blockIdx.x * 8;
    const int t = threadIdx.x;
    const int wave = t >> 6, lane = t & 63;
    {
        const uint4* src = (const uint4*)(bits32 + (size_t)i0 * 256);
        uint4* d = (uint4*)smk;
        d[t] = src[t];
        d[t + 256] = src[t + 256];
    }
    __syncthreads();

    // phase A: per-row masked max of dd
    float mx[8];
#pragma unroll
    for (int r = 0; r < 8; r++) mx[r] = -3.0e38f;
#pragma unroll
    for (int q = 0; q < 8; q++) {
        float4 v = *(const float4*)(dd + 4 * (t + 256 * q));
        const int wq = 32 * q + (t >> 3);
        const int sh = (t & 7) * 4;
#pragma unroll
        for (int r = 0; r < 8; r++) {
            uint32_t b = smk[r * 256 + wq] >> sh;
            mx[r] = fmaxf(mx[r], (b & 1u) ? v.x : -3.0e38f);
            mx[r] = fmaxf(mx[r], (b & 2u) ? v.y : -3.0e38f);
            mx[r] = fmaxf(mx[r], (b & 4u) ? v.z : -3.0e38f);
            mx[r] = fmaxf(mx[r], (b & 8u) ? v.w : -3.0e38f);
        }
    }
#pragma unroll
    for (int r = 0; r < 8; r++) {
#pragma unroll
        for (int off = 32; off; off >>= 1) mx[r] = fmaxf(mx[r], __shfl_down(mx[r], off));
    }
    if (lane == 0) {
#pragma unroll
        for (int r = 0; r < 8; r++) red[wave][r] = mx[r];
    }
    __syncthreads();
    if (t < 8) {
        float dmax = fmaxf(fmaxf(red[0][t], red[1][t]), fmaxf(red[2][t], red[3][t]));
        float si = s[i0 + t];
        float e = si + dmax;
        float m = e >= 0.f ? e : ALPHA * e;
        sM[t] = m;
        sEm[t] = __expf(si - m);
        sEa[t] = __expf(ALPHA * si - m);
    }
    __syncthreads();
    float em[8], ea[8], sm[8];
#pragma unroll
    for (int r = 0; r < 8; r++) { em[r] = sEm[r]; ea[r] = sEa[r]; sm[r] = 0.f; }

    // phase B: per-row masked sum of max(em*F, ea*H)
#pragma unroll
    for (int q = 0; q < 16; q++) {
        float4 v = *(const float4*)(FH + 4 * (t + 256 * q));
        const int wq = 16 * q + (t >> 4);
        const int sh = (t & 15) * 2;
#pragma unroll
        for (int r = 0; r < 8; r++) {
            uint32_t b = smk[r * 256 + wq] >> sh;
            float c0 = fmaxf(em[r] * v.x, ea[r] * v.y);
            float c1 = fmaxf(em[r] * v.z, ea[r] * v.w);
            sm[r] += (b & 1u) ? c0 : 0.f;
            sm[r] += (b & 2u) ? c1 : 0.f;
        }
    }
#pragma unroll
    for (int r = 0; r < 8; r++) {
#pragma unroll
        for (int off = 32; off; off >>= 1) sm[r] += __shfl_down(sm[r], off);
    }
    __syncthreads();
    if (lane == 0) {
#pragma unroll
        for (int r = 0; r < 8; r++) red[wave][r] = sm[r];
    }
    __syncthreads();
    if (t < 8) {
        float rl = 1.0f / (red[0][t] + red[1][t] + red[2][t] + red[3][t]);
        Ep[i0 + t] = rl * sEm[t];
        Gp[i0 + t] = rl * sEa[t];
    }
}

// ---------------- PV via MFMA: pout[ks] = P @ Wh (K-quarter partial) ----------------
// 512 blocks x 256 thr: bx -> ks = bx&3 (K-quarter), ch = (bx>>2)&1 (col half),
// ib = bx>>3 (128-row tile). 4 waves = 2 rg x 2 cg; wave = 64 rows x 64 cols =
// 4 A-frags x 4 B-frags = 16 MFMA/chunk. A in LDS (dbuf, 1 barrier/chunk);
// B-frags register-prefetched one chunk ahead.
__global__ __launch_bounds__(256, 3) void pv_mfma(const unsigned short* __restrict__ Bpack,
                                                  const uint32_t* __restrict__ bitsT,
                                                  const float* __restrict__ FH,
                                                  const float* __restrict__ Ep,
                                                  const float* __restrict__ Gp,
                                                  float* __restrict__ pout) {
    __shared__ __align__(16) unsigned short fragA[2][4096];   // [buf][128 rows x 32 k], 16 KB
    const int t = threadIdx.x;
    const int w = t >> 6, l = t & 63;
    const int bx = blockIdx.x;
    const int ks = bx & 3;
    const int ch = (bx >> 2) & 1;
    const int i0 = (bx >> 3) * 128;
    const int kbase = ks * 64;                    // 64 chunks per quarter
    const int ct0 = ch * 8;                       // 8 col-tiles per block
    const int rg = w >> 1, cg = w & 1;

    // ---- P-gen mapping: thread t -> rows (t&31)+32e (e=0..3), k-quad kq = t>>5 ----
    const int rlane = t & 31;
    const int kq = t >> 5;
    float Epv[4], Gpv[4];
#pragma unroll
    for (int e = 0; e < 4; e++) {
        Epv[e] = Ep[i0 + rlane + 32 * e];
        Gpv[e] = Gp[i0 + rlane + 32 * e];
    }
    const int lanebase = (kq >> 1) * 16 + (rlane & 15);
    const int rbbase = rlane >> 4;                // +2e per e
    const int khi = kq & 1;

    auto gen = [&](int cc, int nbuf) {
        const int jj = cc * 32 + kq * 4;
        float4 fh0 = *(const float4*)(FH + 2 * (size_t)jj);
        float4 fh1 = *(const float4*)(FH + 2 * (size_t)jj + 4);
        const uint32_t* bt = bitsT + (size_t)cc * NN + i0 + rlane;
        uint2* dst = (uint2*)&fragA[nbuf][0];
#pragma unroll
        for (int e = 0; e < 4; e++) {
            uint32_t b = bt[32 * e] >> (kq * 4);
            float p0 = (b & 1u) ? fmaxf(Epv[e] * fh0.x, Gpv[e] * fh0.y) : 0.f;
            float p1 = (b & 2u) ? fmaxf(Epv[e] * fh0.z, Gpv[e] * fh0.w) : 0.f;
            float p2 = (b & 4u) ? fmaxf(Epv[e] * fh1.x, Gpv[e] * fh1.y) : 0.f;
            float p3 = (b & 8u) ? fmaxf(Epv[e] * fh1.z, Gpv[e] * fh1.w) : 0.f;
            uint2 pk;
            pk.x = pk_bf16(p0, p1);
            pk.y = pk_bf16(p2, p3);
            dst[((rbbase + 2 * e) * 64 + lanebase) * 2 + khi] = pk;
        }
    };

    // B base: wave's 4 col-tiles are ct0 + cg*4 .. +3; chunk stride = 16 tiles * 512 shorts
    const unsigned short* bbase = Bpack + ((size_t)(ct0 + cg * 4) * 64 + l) * 8;

    f32x4 acc[4][4];
#pragma unroll
    for (int i = 0; i < 4; i++)
#pragma unroll
        for (int q = 0; q < 4; q++) acc[i][q] = (f32x4){0.f, 0.f, 0.f, 0.f};

    // prologue
    gen(kbase, 0);
    short8 Bc[4];
    {
        const unsigned short* bp = bbase + (size_t)kbase * 8192;
#pragma unroll
        for (int q = 0; q < 4; q++) Bc[q] = *(const short8*)(bp + q * 512);
    }
    __syncthreads();

    for (int jl = 0; jl < 64; jl++) {
        const int buf = jl & 1;
        const int cn = kbase + ((jl + 1) & 63);
        // prefetch next B -> VGPRs (in flight across this iteration's barrier)
        const unsigned short* bp = bbase + (size_t)cn * 8192;
        short8 Bn[4];
#pragma unroll
        for (int q = 0; q < 4; q++) Bn[q] = *(const short8*)(bp + q * 512);
        // generate next P tile into the other LDS buffer
        gen(cn, buf ^ 1);
        // consume current chunk: 4 A-frags x 4 B-frags
        short8 a[4];
#pragma unroll
        for (int ri = 0; ri < 4; ri++)
            a[ri] = *(const short8*)&fragA[buf][((rg * 4 + ri) * 64 + l) * 8];
#pragma unroll
        for (int ri = 0; ri < 4; ri++)
#pragma unroll
            for (int qi = 0; qi < 4; qi++)
                acc[ri][qi] = __builtin_amdgcn_mfma_f32_16x16x32_bf16(a[ri], Bc[qi],
                                                                      acc[ri][qi], 0, 0, 0);
        __syncthreads();
#pragma unroll
        for (int q = 0; q < 4; q++) Bc[q] = Bn[q];
    }

    float* outp = pout + (size_t)ks * NN * DD;
    // C layout: col = l&15, row = (l>>4)*4 + r
#pragma unroll
    for (int ri = 0; ri < 4; ri++) {
        const int orow = i0 + rg * 64 + ri * 16 + (l >> 4) * 4;
#pragma unroll
        for (int qi = 0; qi < 4; qi++) {
            const int ocol = (ct0 + cg * 4 + qi) * 16 + (l & 15);
#pragma unroll
            for (int r = 0; r < 4; r++)
                outp[(size_t)(orow + r) * DD + ocol] = acc[ri][qi][r];
        }
    }
}

// -------- out = relu(p0+p1+p2+p3) --------
__global__ __launch_bounds__(256) void combine4(const float* __restrict__ p,
                                                float* __restrict__ out) {
    const size_t S = (size_t)NN * DD / 4;   // float4 stride between partials
    size_t idx = (size_t)blockIdx.x * 256 + threadIdx.x;
    float4 a = ((const float4*)p)[idx];
    float4 b = ((const float4*)p)[idx + S];
    float4 c = ((const float4*)p)[idx + 2 * S];
    float4 d = ((const float4*)p)[idx + 3 * S];
    float4 o;
    o.x = fmaxf(a.x + b.x + c.x + d.x, 0.f);
    o.y = fmaxf(a.y + b.y + c.y + d.y, 0.f);
    o.z = fmaxf(a.z + b.z + c.z + d.z, 0.f);
    o.w = fmaxf(a.w + b.w + c.w + d.w, 0.f);
    ((float4*)out)[idx] = o;
}

extern "C" void kernel_launch(void* const* d_in, const int* in_sizes, int n_in,
                              void* d_out, int out_size, void* d_ws, size_t ws_size,
                              hipStream_t stream) {
    const float* x   = (const float*)d_in[0];
    const int* adj   = (const int*)d_in[1];
    const float* W1  = (const float*)d_in[2];
    const float* a1s = (const float*)d_in[3];
    const float* a1d = (const float*)d_in[4];
    const float* W2  = (const float*)d_in[5];
    const float* a2s = (const float*)d_in[6];
    const float* a2d = (const float*)d_in[7];
    float* out = (float*)d_out;

    char* ws = (char*)d_ws;
    const size_t MB = 1024ull * 1024ull;
    float*          Wh    = (float*)(ws);                    // 8 MB
    uint64_t*       bits  = (uint64_t*)(ws + 8 * MB);        // 8 MB
    uint32_t*       bits32= (uint32_t*)bits;
    uint32_t*       bitsT = (uint32_t*)(ws + 16 * MB);       // 8 MB
    float*          sArr  = (float*)(ws + 24 * MB);
    float*          ddA   = sArr + NN;
    float*          EpA   = sArr + 2 * NN;
    float*          GpA   = sArr + 3 * NN;
    float*          FHA   = sArr + 4 * NN;                   // 2*NN floats
    unsigned short* Bpack = (unsigned short*)(ws + 25 * MB); // 4 MB
    float*          pout  = (float*)(ws + 32 * MB);          // 32 MB (4 partials)

    packbits<<<dim3(2048), dim3(256), 0, stream>>>(adj, bits);
    transp_bits<<<dim3(512), dim3(256), 0, stream>>>(bits32, bitsT);

    // ---------------- Layer 1 ----------------
    gemm_k256<<<dim3(512), dim3(256), 0, stream>>>(x, W1, Wh, Bpack);
    rowdots<<<dim3(2048), dim3(256), 0, stream>>>(Wh, a1s, a1d, sArr, ddA, FHA);
    rowstats<<<dim3(1024), dim3(256), 0, stream>>>(bits32, sArr, ddA, FHA, EpA, GpA);
    pv_mfma<<<dim3(512), dim3(256), 0, stream>>>(Bpack, bitsT, FHA, EpA, GpA, pout);
    combine4<<<dim3(2048), dim3(256), 0, stream>>>(pout, out);

    // ---------------- Layer 2 ----------------
    gemm_k256<<<dim3(512), dim3(256), 0, stream>>>(out, W2, Wh, Bpack);
    rowdots<<<dim3(2048), dim3(256), 0, stream>>>(Wh, a2s, a2d, sArr, ddA, FHA);
    rowstats<<<dim3(1024), dim3(256), 0, stream>>>(bits32, sArr, ddA, FHA, EpA, GpA);
    pv_mfma<<<dim3(512), dim3(256), 0, stream>>>(Bpack, bitsT, FHA, EpA, GpA, pout);
    combine4<<<dim3(2048), dim3(256), 0, stream>>>(pout, out);
}